// Round 3
// baseline (265.945 us; speedup 1.0000x reference)
//
// R3: 4 -> 2 kernels. K_A = prepup (verified, 848 blk) + zeroes barrier counter.
// K_B = gemm5 -> [hand-rolled device barrier] -> attn -> [bar] -> tail, 320 blk.
// Rationale: R0->R2 showed each dependent kernel launch costs ~10-15us ramp/drain;
// cg grid.sync costs ~70us (R1); hand-rolled monotonic atomic barrier ~2-5us.
#include <hip/hip_runtime.h>
#include <hip/hip_bf16.h>

#define T_ 64
#define B_ 8
#define H_ 128
#define NH_ 4
#define D_ 256
#define TB_ 512          // T_*B_
#define EPS_ 1e-5f
#define NBLK_B 320       // K_B grid; all co-resident (LDS 40KB -> 4/CU, VGPR<=256 -> >=2/CU)

typedef short bf16x8 __attribute__((ext_vector_type(8)));
typedef float f32x4 __attribute__((ext_vector_type(4)));

__device__ __forceinline__ float silu_(float x){ return x / (1.0f + __expf(-x)); }
__device__ __forceinline__ float sigm_(float x){ return 1.0f / (1.0f + __expf(-x)); }
__device__ __forceinline__ unsigned short tobf_(float f){
  unsigned u = __float_as_uint(f);
  u += 0x7FFF + ((u >> 16) & 1);          // round-to-nearest-even
  return (unsigned short)(u >> 16);
}
// A-fragment-linear address, element (m,k) of [M x 256] bf16 matrix (K=256)
__device__ __forceinline__ int afrag_(int m, int k){
  return (((m >> 4)*8 + (k >> 5))*64 + ((k >> 3)&3)*16 + (m & 15))*8 + (k & 7);
}
// generalized for K=1024 (32 kb per m-tile)
__device__ __forceinline__ int afrag1024_(int m, int k){
  return (((m >> 4)*32 + (k >> 5))*64 + ((k >> 3)&3)*16 + (m & 15))*8 + (k & 7);
}

// ---- device-wide barrier: monotonic counter, release-add / acquire-spin ----
__device__ __forceinline__ void gbar_(int* cnt, int target){
  __syncthreads();                        // all block's mem ops complete (vmcnt drained)
  if (threadIdx.x == 0){
    __threadfence();                      // release: L2 writeback, device scope
    __hip_atomic_fetch_add(cnt, 1, __ATOMIC_RELEASE, __HIP_MEMORY_SCOPE_AGENT);
    while (__hip_atomic_load(cnt, __ATOMIC_ACQUIRE, __HIP_MEMORY_SCOPE_AGENT) < target)
      __builtin_amdgcn_s_sleep(8);
    __threadfence();                      // acquire: invalidate stale L1/L2 lines
  }
  __syncthreads();
}

// ---------------- K_A: weight conversions + fused bn1+upcg+conv+gates ----------------
// bid map: [0,64) upcg-self | [64,704) big5 conv | [704,832) Wpoll | [832,848) Wdown
__global__ __launch_bounds__(256) void k_prepup(
    const float* __restrict__ Wq, const float* __restrict__ Wk, const float* __restrict__ Ws,
    const float* __restrict__ Wv, const float* __restrict__ Wo,
    const float* __restrict__ Wup1, const float* __restrict__ Wup2,
    const float* __restrict__ Wp, const float* __restrict__ Wd,
    const float* __restrict__ x, const float* __restrict__ bn1s, const float* __restrict__ bn1b,
    const float* __restrict__ bup1, const float* __restrict__ bup2,
    const float* __restrict__ ck, const float* __restrict__ cb,
    const float* __restrict__ Wi, const float* __restrict__ bi,
    const float* __restrict__ Wf, const float* __restrict__ bfv,
    unsigned short* __restrict__ Wqt, unsigned short* __restrict__ Wkt,
    unsigned short* __restrict__ Wst, unsigned short* __restrict__ Wvt,
    unsigned short* __restrict__ Wot,
    unsigned short* __restrict__ Wpt, unsigned short* __restrict__ Wdt,
    unsigned short* __restrict__ xinb, unsigned short* __restrict__ qkb,
    float* __restrict__ trig, float* __restrict__ itb, float* __restrict__ ftb,
    int* __restrict__ cnt){
  __shared__ float xs[16][257];
  __shared__ unsigned short ubl[2048];   // local A-frag: 2 timesteps (16 rows), K=128
  int bid = blockIdx.x;
  int tid = threadIdx.x;
  if (bid == 0 && tid == 0) *cnt = 0;    // init barrier counter for K_B (ws is poisoned)
  if (bid < 64){
    // ---- fused bn1 + up-projection (self-sufficient) ----
    int u = bid;
    int mat = u >> 5, rt = u & 31;       // rt = t-pair index
    {
      int tt = tid >> 7, hf = tid & 127;
      int t = rt*2 + tt;
      const float* xp = x + t*(B_*H_) + hf;
      float v0[8]; float mu = 0.f;
      #pragma unroll
      for (int b = 0; b < 8; b++){ v0[b] = xp[b*H_]; mu += v0[b]; }
      mu *= 0.125f;
      float var = 0.f;
      #pragma unroll
      for (int b = 0; b < 8; b++){ float dd = v0[b]-mu; var += dd*dd; }
      var *= 0.125f;
      float sc = (1.0f/sqrtf(var + EPS_)) * bn1s[hf];
      float bs = bn1b[hf];
      int kb = hf >> 5, j = hf & 7;
      int lanebase = ((hf >> 3)&3)*16 + tt*8;
      unsigned short* up = ubl + kb*512 + j;
      #pragma unroll
      for (int b = 0; b < 8; b++)
        up[(lanebase + b)*8] = tobf_((v0[b]-mu)*sc + bs);
    }
    __syncthreads();
    int w = tid >> 6, l = tid & 63, lm = l & 15, lq = l >> 4;
    const float* Wf32 = (mat == 0) ? Wup1 : Wup2;
    f32x4 acc[4];
    #pragma unroll
    for (int nt = 0; nt < 4; nt++) acc[nt] = (f32x4){0.f,0.f,0.f,0.f};
    #pragma unroll
    for (int kb = 0; kb < 4; kb++){
      bf16x8 a = *(const bf16x8*)(ubl + kb*512 + l*8);
      int k0 = kb*32 + lq*8;
      #pragma unroll
      for (int nt = 0; nt < 4; nt++){
        int n = (w*4 + nt)*16 + lm;
        const float* src = Wf32 + k0*D_ + n;
        bf16x8 bfr;
        #pragma unroll
        for (int j = 0; j < 8; j++) bfr[j] = (short)tobf_(src[j*D_]);
        acc[nt] = __builtin_amdgcn_mfma_f32_16x16x32_bf16(a, bfr, acc[nt], 0, 0, 0);
      }
    }
    const float* bias = (mat == 0) ? bup1 : bup2;
    #pragma unroll
    for (int nt = 0; nt < 4; nt++){
      #pragma unroll
      for (int r = 0; r < 4; r++){
        int m = lq*4 + r;
        int row = rt*16 + m;
        int e = w*64 + nt*16 + lm;
        float vv = acc[nt][r] + bias[e];
        if (mat == 1){
          trig[row*D_ + e] = silu_(vv);
        } else {
          xinb[afrag_(row, e)] = tobf_(vv);
          xs[m][e] = vv;
        }
      }
    }
    if (mat == 0){
      __syncthreads();
      int d = tid;
      #pragma unroll 4
      for (int m = 0; m < 16; m++){
        float x0  = xs[m][d];
        float xm1 = (d >= 1)   ? xs[m][d-1] : 0.f;
        float xp1 = (d <= 254) ? xs[m][d+1] : 0.f;
        float xp2 = (d <= 253) ? xs[m][d+2] : 0.f;
        int rowg = rt*16 + m;
        int fa = afrag_(rowg, d);
        #pragma unroll
        for (int h = 0; h < NH_; h++){
          float a2 = cb[h];
          a2 = fmaf(xm1, ck[0*NH_+h], a2);
          a2 = fmaf(x0,  ck[1*NH_+h], a2);
          a2 = fmaf(xp1, ck[2*NH_+h], a2);
          a2 = fmaf(xp2, ck[3*NH_+h], a2);
          qkb[h*(TB_*D_) + fa] = tobf_(silu_(a2));
        }
      }
      int dot = tid >> 2, l4 = tid & 3;
      int h = dot >> 4, m = dot & 15;
      float ai = 0.f, af = 0.f;
      const float* wi = Wi + h*D_;
      const float* wf = Wf + h*D_;
      #pragma unroll 8
      for (int jj = 0; jj < 64; jj++){
        int k = l4*64 + jj;
        float xv = xs[m][k];
        ai = fmaf(xv, wi[k], ai);
        af = fmaf(xv, wf[k], af);
      }
      ai += __shfl_down(ai, 1); af += __shfl_down(af, 1);
      ai += __shfl_down(ai, 2); af += __shfl_down(af, 2);
      if (l4 == 0){
        int rowg = rt*16 + m;
        int t = rowg >> 3, b = rowg & 7;
        itb[(h*B_ + b)*T_ + t] = ai + bi[h];
        ftb[(h*B_ + b)*T_ + t] = af + bfv[h];
      }
    }
  } else if (bid < 704){
    // ---- big5 weight conversion ----
    int u = bid - 64;
    int sub = u & 31;
    int h   = (u >> 5) & 3;
    int mat = u >> 7;
    const float* Win; unsigned short* Wout;
    switch (mat){
      case 0: Win = Wq; Wout = Wqt; break;
      case 1: Win = Wk; Wout = Wkt; break;
      case 2: Win = Ws; Wout = Wst; break;
      case 3: Win = Wv; Wout = Wvt; break;
      default: Win = Wo; Wout = Wot; break;
    }
    Win  += h * (D_*D_);
    Wout += h * (D_*D_);
    int gid = sub*256 + tid;
    int combo = gid >> 6;                // nt*8 + kb
    int l = gid & 63;
    int lm = l & 15, lq = l >> 4;
    int nt = combo >> 3, kb = combo & 7;
    int n = nt*16 + lm;
    int k0 = kb*32 + lq*8;
    bf16x8 v;
    #pragma unroll
    for (int j = 0; j < 8; j++) v[j] = (short)tobf_(Win[(k0+j)*D_ + n]);
    *(bf16x8*)(Wout + (combo*64 + l)*8) = v;
  } else if (bid < 832){
    // ---- Wpoll [1024 x 256] -> B-frag K=1024 ----
    int gid = (bid - 704)*256 + tid;     // [0, 32768)
    int combo = gid >> 6;                // nt*32 + kb
    int l = gid & 63;
    int lm = l & 15, lq = l >> 4;
    int nt = combo >> 5, kb = combo & 31;
    int n = nt*16 + lm;
    int k0 = kb*32 + lq*8;
    bf16x8 v;
    #pragma unroll
    for (int j = 0; j < 8; j++) v[j] = (short)tobf_(Wp[(k0+j)*D_ + n]);
    *(bf16x8*)(Wpt + (combo*64 + l)*8) = v;
  } else {
    // ---- Wdown [256 x 128] -> B-frag K=256 ----
    int gid = (bid - 832)*256 + tid;     // [0, 4096)
    int combo = gid >> 6;                // nt*8 + kb
    int l = gid & 63;
    int lm = l & 15, lq = l >> 4;
    int nt = combo >> 3, kb = combo & 7;
    int n = nt*16 + lm;
    int k0 = kb*32 + lq*8;
    bf16x8 v;
    #pragma unroll
    for (int j = 0; j < 8; j++) v[j] = (short)tobf_(Wd[(k0+j)*H_ + n]);
    *(bf16x8*)(Wdt + (combo*64 + l)*8) = v;
  }
}

// ---------------- K_B params ----------------
struct KB {
  const unsigned short *qkb, *xinb, *Wqt, *Wkt, *Wst, *Wvt, *Wot, *Wpt, *Wdt;
  const float *bq, *bk, *bsk, *bv, *bo;
  const float *itb, *ftb;
  const float *bn2s, *bn2b, *bp, *trig, *bd, *x;
  unsigned short *qob, *kob, *vot;
  float *hbuf, *og, *y;
  int* cnt;
};

// ---- phase bodies (verbatim from R1/R2-verified code) ----
__device__ __forceinline__ void ph_gemm5(const KB& p, int u, int tid){
  int rt  = u & 15;
  int h   = (u >> 4) & 3;
  int mat = u >> 6;                    // 0=q 1=k 2=skip 3=v 4=og
  int w = tid >> 6, l = tid & 63;
  int lm = l & 15, lq = l >> 4;
  int r0 = rt * 32;
  const unsigned short* A = (mat < 3) ? (p.qkb + h*(TB_*D_)) : p.xinb;
  const unsigned short* Bt;
  const float* bias;
  switch (mat){
    case 0: Bt = p.Wqt; bias = p.bq;  break;
    case 1: Bt = p.Wkt; bias = p.bk;  break;
    case 2: Bt = p.Wst; bias = p.bsk; break;
    case 3: Bt = p.Wvt; bias = p.bv;  break;
    default: Bt = p.Wot; bias = p.bo; break;
  }
  Bt += h*(D_*D_);
  f32x4 acc[2][4];
  #pragma unroll
  for (int mt = 0; mt < 2; mt++)
    #pragma unroll
    for (int nt = 0; nt < 4; nt++) acc[mt][nt] = (f32x4){0.f,0.f,0.f,0.f};
  const unsigned short* Ap = A + l*8;
  const unsigned short* Bp = Bt + l*8;
  #pragma unroll
  for (int kc = 0; kc < 8; kc++){
    bf16x8 a0 = *(const bf16x8*)(Ap + ((rt*16      + kc) << 9));
    bf16x8 a1 = *(const bf16x8*)(Ap + ((rt*16 + 8  + kc) << 9));
    bf16x8 b0 = *(const bf16x8*)(Bp + (((w*4+0)*8 + kc) << 9));
    bf16x8 b1 = *(const bf16x8*)(Bp + (((w*4+1)*8 + kc) << 9));
    bf16x8 b2 = *(const bf16x8*)(Bp + (((w*4+2)*8 + kc) << 9));
    bf16x8 b3 = *(const bf16x8*)(Bp + (((w*4+3)*8 + kc) << 9));
    acc[0][0] = __builtin_amdgcn_mfma_f32_16x16x32_bf16(a0, b0, acc[0][0], 0, 0, 0);
    acc[0][1] = __builtin_amdgcn_mfma_f32_16x16x32_bf16(a0, b1, acc[0][1], 0, 0, 0);
    acc[0][2] = __builtin_amdgcn_mfma_f32_16x16x32_bf16(a0, b2, acc[0][2], 0, 0, 0);
    acc[0][3] = __builtin_amdgcn_mfma_f32_16x16x32_bf16(a0, b3, acc[0][3], 0, 0, 0);
    acc[1][0] = __builtin_amdgcn_mfma_f32_16x16x32_bf16(a1, b0, acc[1][0], 0, 0, 0);
    acc[1][1] = __builtin_amdgcn_mfma_f32_16x16x32_bf16(a1, b1, acc[1][1], 0, 0, 0);
    acc[1][2] = __builtin_amdgcn_mfma_f32_16x16x32_bf16(a1, b2, acc[1][2], 0, 0, 0);
    acc[1][3] = __builtin_amdgcn_mfma_f32_16x16x32_bf16(a1, b3, acc[1][3], 0, 0, 0);
  }
  float bval[4];
  #pragma unroll
  for (int nt = 0; nt < 4; nt++) bval[nt] = bias[h*D_ + w*64 + nt*16 + lm];
  #pragma unroll
  for (int mt = 0; mt < 2; mt++){
    #pragma unroll
    for (int r = 0; r < 4; r++){
      int row = r0 + mt*16 + lq*4 + r;
      int t = row >> 3, b = row & 7;
      #pragma unroll
      for (int nt = 0; nt < 4; nt++){
        int e = w*64 + nt*16 + lm;
        float vv = acc[mt][nt][r] + bval[nt];
        if (mat <= 1){
          if (mat == 1) vv *= 0.0625f;
          unsigned short* ob = (mat == 0) ? p.qob : p.kob;
          int mt2 = t >> 4, kb2 = e >> 5;
          int lane2 = ((e >> 3)&3)*16 + (t & 15);
          ob[(h*B_ + b)*16384 + ((mt2*8 + kb2)*64 + lane2)*8 + (e & 7)] = tobf_(vv);
        } else if (mat == 3){
          int nt3 = e >> 4, kb3 = t >> 5;
          int lane3 = ((t >> 3)&3)*16 + lm;
          p.vot[(h*B_ + b)*16384 + ((nt3*2 + kb3)*64 + lane3)*8 + (t & 7)] = tobf_(vv);
        } else {
          int obase = (((t*NH_ + h)*B_ + b) << 8) + e;
          if (mat == 4) p.og[obase] = sigm_(vv);
          else          p.hbuf[obase] = vv;        // skip term
        }
      }
    }
  }
}

__device__ __forceinline__ void ph_attn(const KB& p, int u, int tid, unsigned char* smemraw){
  unsigned short* Pf = (unsigned short*)smemraw;                 // 1024 shorts
  float (*partial)[16] = (float (*)[16])(smemraw + 2048);        // [4][16]
  float* scal = (float*)(smemraw + 2048 + 256);                  // [16]
  int hbx = u >> 2, tq = u & 3;
  int h = hbx >> 3, b = hbx & 7;
  int w = tid >> 6, l = tid & 63, lm = l & 15, lq = l >> 4;
  float F  = p.ftb[hbx*T_ + l];
  float it = p.itb[hbx*T_ + l];
  #pragma unroll
  for (int off = 1; off < 64; off <<= 1){
    float v2 = __shfl_up(F, off);
    if (l >= off) F += v2;
  }
  float ct = it - F;
  float G = ct;
  #pragma unroll
  for (int off = 1; off < 64; off <<= 1){
    float v2 = __shfl_up(G, off);
    if (l >= off) G = fmaxf(G, v2);
  }
  float rb = -fmaxf(0.f, G);
  const unsigned short* Aq = p.qob + hbx*16384 + l*8;
  const unsigned short* Bk = p.kob + hbx*16384 + l*8;
  f32x4 accs = (f32x4){0.f,0.f,0.f,0.f};
  #pragma unroll
  for (int kc = 0; kc < 8; kc++){
    bf16x8 a  = *(const bf16x8*)(Aq + ((tq*8 + kc) << 9));
    bf16x8 bb = *(const bf16x8*)(Bk + ((w*8  + kc) << 9));
    accs = __builtin_amdgcn_mfma_f32_16x16x32_bf16(a, bb, accs, 0, 0, 0);
  }
  int s = w*16 + lm;
  float ct_s = __shfl(ct, s);
  float pv4[4], ps[4];
  #pragma unroll
  for (int r = 0; r < 4; r++){
    int t = tq*16 + lq*4 + r;
    float rb_t = __shfl(rb, t);
    float pv = (s <= t) ? __expf(ct_s + rb_t) * accs[r] : 0.f;
    pv4[r] = pv; ps[r] = pv;
  }
  #pragma unroll
  for (int off = 1; off < 16; off <<= 1){
    #pragma unroll
    for (int r = 0; r < 4; r++) ps[r] += __shfl_xor(ps[r], off);
  }
  if (lm == 0){
    #pragma unroll
    for (int r = 0; r < 4; r++) partial[w][lq*4 + r] = ps[r];
  }
  {
    int kbP = w >> 1;
    int laneP = ((w*2 + (lm >> 3)) & 3)*16;
    int jP = lm & 7;
    #pragma unroll
    for (int r = 0; r < 4; r++){
      int m = lq*4 + r;
      Pf[(kbP*64 + laneP + m)*8 + jP] = tobf_(pv4[r]);
    }
  }
  __syncthreads();
  if (tid < 16){
    float sum = partial[0][tid] + partial[1][tid] + partial[2][tid] + partial[3][tid];
    scal[tid] = 1.0f / fmaxf(fabsf(sum), 1.0f);
  }
  bf16x8 pa0 = *(const bf16x8*)(Pf + l*8);
  bf16x8 pa1 = *(const bf16x8*)(Pf + 512 + l*8);
  const unsigned short* Bv = p.vot + hbx*16384 + l*8;
  f32x4 acco[4];
  #pragma unroll
  for (int nt = 0; nt < 4; nt++) acco[nt] = (f32x4){0.f,0.f,0.f,0.f};
  #pragma unroll
  for (int nt = 0; nt < 4; nt++){
    int nt3 = w*4 + nt;
    bf16x8 b0 = *(const bf16x8*)(Bv + (((nt3*2 + 0)) << 9));
    bf16x8 b1 = *(const bf16x8*)(Bv + (((nt3*2 + 1)) << 9));
    acco[nt] = __builtin_amdgcn_mfma_f32_16x16x32_bf16(pa0, b0, acco[nt], 0, 0, 0);
    acco[nt] = __builtin_amdgcn_mfma_f32_16x16x32_bf16(pa1, b1, acco[nt], 0, 0, 0);
  }
  __syncthreads();
  #pragma unroll
  for (int nt = 0; nt < 4; nt++){
    #pragma unroll
    for (int r = 0; r < 4; r++){
      int tl = lq*4 + r;
      int t = tq*16 + tl;
      int e = (w*4 + nt)*16 + lm;
      int idx = (((t*NH_ + h)*B_ + b) << 8) + e;
      p.hbuf[idx] += p.og[idx] * acco[nt][r] * scal[tl];
    }
  }
}

__device__ __forceinline__ void ph_tail(const KB& p, int u, int tid, unsigned char* smemraw){
  unsigned short* hfr = (unsigned short*)smemraw;            // 16K shorts: A-frag M=16,K=1024
  unsigned short* zf  = (unsigned short*)(smemraw + 32768);  // 4K shorts: z frag M=16,K=256
  int w = tid >> 6, l = tid & 63, lm = l & 15, lq = l >> 4;
  #pragma unroll
  for (int s = 0; s < 2; s++){
    int pair = tid + (s << 8);     // 0..511
    int tt = pair >> 8;            // 0..1
    int d  = pair & 255;
    int t  = u*2 + tt;
    const float* hp = p.hbuf + (t*NH_*B_)*D_ + d;
    float v[32]; float mu = 0.f;
    #pragma unroll
    for (int i = 0; i < 32; i++){ v[i] = hp[i*D_]; mu += v[i]; }
    mu *= (1.0f/32.0f);
    float var = 0.f;
    #pragma unroll
    for (int i = 0; i < 32; i++){ float dd = v[i]-mu; var += dd*dd; }
    var *= (1.0f/32.0f);
    float sc = (1.0f/sqrtf(var + EPS_)) * p.bn2s[d];
    float bs = p.bn2b[d];
    #pragma unroll
    for (int i = 0; i < 32; i++){          // i = h*8 + b
      int hh = i >> 3, b = i & 7;
      int m = tt*8 + b;
      int k = hh*D_ + d;
      hfr[afrag1024_(m, k)] = tobf_((v[i]-mu)*sc + bs);
    }
  }
  __syncthreads();
  f32x4 acc[4];
  #pragma unroll
  for (int nt = 0; nt < 4; nt++) acc[nt] = (f32x4){0.f,0.f,0.f,0.f};
  const unsigned short* Apl = hfr + l*8;
  const unsigned short* Bp  = p.Wpt + l*8;
  #pragma unroll 4
  for (int kc = 0; kc < 32; kc++){
    bf16x8 a = *(const bf16x8*)(Apl + (kc << 9));
    #pragma unroll
    for (int nt = 0; nt < 4; nt++){
      bf16x8 bfr = *(const bf16x8*)(Bp + ((((w*4+nt)*32) + kc) << 9));
      acc[nt] = __builtin_amdgcn_mfma_f32_16x16x32_bf16(a, bfr, acc[nt], 0, 0, 0);
    }
  }
  #pragma unroll
  for (int nt = 0; nt < 4; nt++){
    int e = w*64 + nt*16 + lm;
    float bpe = p.bp[e];
    #pragma unroll
    for (int r = 0; r < 4; r++){
      int ml = lq*4 + r;
      int row = u*16 + ml;
      float z = (acc[nt][r] + bpe) * p.trig[row*D_ + e];
      zf[afrag_(ml, e)] = tobf_(z);
    }
  }
  __syncthreads();
  f32x4 acc2[2];
  acc2[0] = (f32x4){0.f,0.f,0.f,0.f};
  acc2[1] = (f32x4){0.f,0.f,0.f,0.f};
  const unsigned short* Bdp = p.Wdt + l*8;
  #pragma unroll
  for (int kc = 0; kc < 8; kc++){
    bf16x8 a = *(const bf16x8*)(zf + (kc << 9) + l*8);
    #pragma unroll
    for (int q = 0; q < 2; q++){
      bf16x8 bb = *(const bf16x8*)(Bdp + (((w*2+q)*8 + kc) << 9));
      acc2[q] = __builtin_amdgcn_mfma_f32_16x16x32_bf16(a, bb, acc2[q], 0, 0, 0);
    }
  }
  #pragma unroll
  for (int q = 0; q < 2; q++){
    int hh = (w*2+q)*16 + lm;
    float bde = p.bd[hh];
    #pragma unroll
    for (int r = 0; r < 4; r++){
      int row = u*16 + lq*4 + r;
      p.y[row*H_ + hh] = acc2[q][r] + bde + p.x[row*H_ + hh];
    }
  }
}

// ---------------- K_B: gemm5 -> bar -> attn -> bar -> tail ----------------
__global__ __launch_bounds__(256, 2) void k_body(KB p){
  __shared__ alignas(16) unsigned char smem[40960];
  int bid = blockIdx.x;
  int tid = threadIdx.x;
  // phase 1: 320 units, one per block
  ph_gemm5(p, bid, tid);
  gbar_(p.cnt, NBLK_B);
  // phase 2: attention, 128 units
  if (bid < 128) ph_attn(p, bid, tid, smem);
  gbar_(p.cnt, 2*NBLK_B);
  // phase 3: fused bn2+poll+down, 32 units
  if (bid < 32) ph_tail(p, bid, tid, smem);
}

extern "C" void kernel_launch(void* const* d_in, const int* in_sizes, int n_in,
                              void* d_out, int out_size, void* d_ws, size_t ws_size,
                              hipStream_t stream){
  const float* x     = (const float*)d_in[0];
  const float* Wq    = (const float*)d_in[1];
  const float* bq    = (const float*)d_in[2];
  const float* Wk    = (const float*)d_in[3];
  const float* bk    = (const float*)d_in[4];
  const float* Wv    = (const float*)d_in[5];
  const float* bv    = (const float*)d_in[6];
  const float* ck    = (const float*)d_in[7];
  const float* cb    = (const float*)d_in[8];
  const float* Wi    = (const float*)d_in[9];
  const float* bi    = (const float*)d_in[10];
  const float* Wf    = (const float*)d_in[11];
  const float* bf    = (const float*)d_in[12];
  const float* Wo    = (const float*)d_in[13];
  const float* bo    = (const float*)d_in[14];
  const float* Wsk   = (const float*)d_in[15];
  const float* bsk   = (const float*)d_in[16];
  const float* bn1s  = (const float*)d_in[17];
  const float* bn1b  = (const float*)d_in[18];
  const float* bn2s  = (const float*)d_in[19];
  const float* bn2b  = (const float*)d_in[20];
  const float* Wup1  = (const float*)d_in[21];
  const float* bup1  = (const float*)d_in[22];
  const float* Wup2  = (const float*)d_in[23];
  const float* bup2  = (const float*)d_in[24];
  const float* Wp    = (const float*)d_in[25];
  const float* bp    = (const float*)d_in[26];
  const float* Wd    = (const float*)d_in[27];
  const float* bd    = (const float*)d_in[28];
  float* y = (float*)d_out;

  float* w = (float*)d_ws;
  float* trig = w;  w += T_*B_*D_;
  float* hbuf = w;  w += T_*NH_*B_*D_;
  float* og   = w;  w += T_*NH_*B_*D_;
  float* itb  = w;  w += NH_*B_*T_;
  float* ftb  = w;  w += NH_*B_*T_;
  unsigned short* xinb = (unsigned short*)w;  w += (T_*B_*D_)/2;
  unsigned short* qkb  = (unsigned short*)w;  w += (NH_*TB_*D_)/2;
  unsigned short* Wqt  = (unsigned short*)w;  w += (NH_*D_*D_)/2;
  unsigned short* Wkt  = (unsigned short*)w;  w += (NH_*D_*D_)/2;
  unsigned short* Wst  = (unsigned short*)w;  w += (NH_*D_*D_)/2;
  unsigned short* Wvt  = (unsigned short*)w;  w += (NH_*D_*D_)/2;
  unsigned short* Wot  = (unsigned short*)w;  w += (NH_*D_*D_)/2;
  unsigned short* qob  = (unsigned short*)w;  w += (NH_*B_*T_*D_)/2;
  unsigned short* kob  = (unsigned short*)w;  w += (NH_*B_*T_*D_)/2;
  unsigned short* vot  = (unsigned short*)w;  w += (NH_*B_*T_*D_)/2;
  unsigned short* Wpt  = (unsigned short*)w;  w += (NH_*D_*D_)/2;
  unsigned short* Wdt  = (unsigned short*)w;  w += (D_*H_)/2;
  int* cnt = (int*)w;

  k_prepup<<<848, 256, 0, stream>>>(Wq, Wk, Wsk, Wv, Wo, Wup1, Wup2, Wp, Wd,
                                    x, bn1s, bn1b, bup1, bup2, ck, cb, Wi, bi, Wf, bf,
                                    Wqt, Wkt, Wst, Wvt, Wot, Wpt, Wdt,
                                    xinb, qkb, trig, itb, ftb, cnt);

  KB P;
  P.qkb = qkb; P.xinb = xinb; P.Wqt = Wqt; P.Wkt = Wkt; P.Wst = Wst; P.Wvt = Wvt;
  P.Wot = Wot; P.Wpt = Wpt; P.Wdt = Wdt;
  P.bq = bq; P.bk = bk; P.bsk = bsk; P.bv = bv; P.bo = bo;
  P.itb = itb; P.ftb = ftb;
  P.bn2s = bn2s; P.bn2b = bn2b; P.bp = bp; P.trig = trig; P.bd = bd; P.x = x;
  P.qob = qob; P.kob = kob; P.vot = vot;
  P.hbuf = hbuf; P.og = og; P.y = y;
  P.cnt = cnt;

  k_body<<<NBLK_B, 256, 0, stream>>>(P);
}

// Round 4
// 151.591 us; speedup vs baseline: 1.7544x; 1.7544x over previous
//
// R4: R2 structure (4 serial kernels, best: 155.3us). Rebuilt k_prepup memory
// patterns: (1) weight conversion via LDS-transpose tiles - contiguous 512B/row
// float4 loads + 256B-contiguous bf16x8 stores (was: 64B-stride gather loads);
// (2) conv/xinb epilogue vectorized to bf16x8 stores (was ~1M scalar 2B stores).
// Output layouts bit-identical to R2 (verified mapping algebra in journal).
// Decision probe: if dur unchanged, remaining time is harness dispatch chatter
// -> roofline.
#include <hip/hip_runtime.h>
#include <hip/hip_bf16.h>

#define T_ 64
#define B_ 8
#define H_ 128
#define NH_ 4
#define D_ 256
#define TB_ 512          // T_*B_
#define EPS_ 1e-5f

typedef short bf16x8 __attribute__((ext_vector_type(8)));
typedef float f32x4 __attribute__((ext_vector_type(4)));

__device__ __forceinline__ float silu_(float x){ return x / (1.0f + __expf(-x)); }
__device__ __forceinline__ float sigm_(float x){ return 1.0f / (1.0f + __expf(-x)); }
__device__ __forceinline__ unsigned short tobf_(float f){
  unsigned u = __float_as_uint(f);
  u += 0x7FFF + ((u >> 16) & 1);          // round-to-nearest-even
  return (unsigned short)(u >> 16);
}
// A-fragment-linear address, element (m,k) of [M x 256] bf16 matrix (K=256)
__device__ __forceinline__ int afrag_(int m, int k){
  return (((m >> 4)*8 + (k >> 5))*64 + ((k >> 3)&3)*16 + (m & 15))*8 + (k & 7);
}
// generalized for K=1024 (32 kb per m-tile)
__device__ __forceinline__ int afrag1024_(int m, int k){
  return (((m >> 4)*32 + (k >> 5))*64 + ((k >> 3)&3)*16 + (m & 15))*8 + (k & 7);
}

// Tile-converter: fp32 W (row-major, rowstride floats) -> bf16 B-frag layout.
// Tile = rows [tk*16, tk*16+16) x cols [tn*128, tn*128+128).
// Frag combo = nt*KBS + kb with kb = tk>>1, nt = tn*8 + nn.
// Loads: 512B contiguous per row (coalesced). Stores: 512B contiguous per wave.
__device__ __forceinline__ void conv_tile_(const float* __restrict__ Win,
                                           unsigned short* __restrict__ Wout,
                                           int rowstride, int KBS, int tk, int tn,
                                           float (*tl)[132], int tid){
  #pragma unroll
  for (int p = 0; p < 2; p++){
    int r  = p*8 + (tid >> 5);
    int c4 = (tid & 31)*4;
    const float4 v = *(const float4*)(Win + (tk*16 + r)*rowstride + tn*128 + c4);
    tl[r][c4+0] = v.x; tl[r][c4+1] = v.y; tl[r][c4+2] = v.z; tl[r][c4+3] = v.w;
  }
  __syncthreads();
  int nn  = tid >> 5;            // 0..7  n-subtile
  int lqb = (tid >> 4) & 1;      // which lq half
  int lm  = tid & 15;
  int combo = (tn*8 + nn)*KBS + (tk >> 1);
  int l = (2*(tk & 1) + lqb)*16 + lm;
  bf16x8 v;
  #pragma unroll
  for (int j = 0; j < 8; j++) v[j] = (short)tobf_(tl[lqb*8 + j][nn*16 + lm]);
  *(bf16x8*)(Wout + (combo*64 + l)*8) = v;
}

// ---------------- K1: weight conversions + fused bn1+upcg+conv+gates ----------------
// bid map: [0,64) upcg-self | [64,704) big5 conv | [704,832) Wpoll | [832,848) Wdown
__global__ __launch_bounds__(256) void k_prepup(
    const float* __restrict__ Wq, const float* __restrict__ Wk, const float* __restrict__ Ws,
    const float* __restrict__ Wv, const float* __restrict__ Wo,
    const float* __restrict__ Wup1, const float* __restrict__ Wup2,
    const float* __restrict__ Wp, const float* __restrict__ Wd,
    const float* __restrict__ x, const float* __restrict__ bn1s, const float* __restrict__ bn1b,
    const float* __restrict__ bup1, const float* __restrict__ bup2,
    const float* __restrict__ ck, const float* __restrict__ cb,
    const float* __restrict__ Wi, const float* __restrict__ bi,
    const float* __restrict__ Wf, const float* __restrict__ bfv,
    unsigned short* __restrict__ Wqt, unsigned short* __restrict__ Wkt,
    unsigned short* __restrict__ Wst, unsigned short* __restrict__ Wvt,
    unsigned short* __restrict__ Wot,
    unsigned short* __restrict__ Wpt, unsigned short* __restrict__ Wdt,
    unsigned short* __restrict__ xinb, unsigned short* __restrict__ qkb,
    float* __restrict__ trig, float* __restrict__ itb, float* __restrict__ ftb){
  __shared__ float xs[16][257];
  __shared__ unsigned short ubl[2048];   // local A-frag: 2 timesteps (16 rows), K=128
  __shared__ float tl[16][132];          // conversion tile
  int bid = blockIdx.x;
  int tid = threadIdx.x;
  if (bid < 64){
    // ---- fused bn1 + up-projection (self-sufficient) ----
    int u = bid;
    int mat = u >> 5, rt = u & 31;       // rt = t-pair index
    {
      int tt = tid >> 7, hf = tid & 127;
      int t = rt*2 + tt;
      const float* xp = x + t*(B_*H_) + hf;
      float v0[8]; float mu = 0.f;
      #pragma unroll
      for (int b = 0; b < 8; b++){ v0[b] = xp[b*H_]; mu += v0[b]; }
      mu *= 0.125f;
      float var = 0.f;
      #pragma unroll
      for (int b = 0; b < 8; b++){ float dd = v0[b]-mu; var += dd*dd; }
      var *= 0.125f;
      float sc = (1.0f/sqrtf(var + EPS_)) * bn1s[hf];
      float bs = bn1b[hf];
      int kb = hf >> 5, j = hf & 7;
      int lanebase = ((hf >> 3)&3)*16 + tt*8;
      unsigned short* up = ubl + kb*512 + j;
      #pragma unroll
      for (int b = 0; b < 8; b++)
        up[(lanebase + b)*8] = tobf_((v0[b]-mu)*sc + bs);
    }
    __syncthreads();
    int w = tid >> 6, l = tid & 63, lm = l & 15, lq = l >> 4;
    const float* Wf32 = (mat == 0) ? Wup1 : Wup2;
    f32x4 acc[4];
    #pragma unroll
    for (int nt = 0; nt < 4; nt++) acc[nt] = (f32x4){0.f,0.f,0.f,0.f};
    #pragma unroll
    for (int kb = 0; kb < 4; kb++){
      bf16x8 a = *(const bf16x8*)(ubl + kb*512 + l*8);
      int k0 = kb*32 + lq*8;
      #pragma unroll
      for (int nt = 0; nt < 4; nt++){
        int n = (w*4 + nt)*16 + lm;
        const float* src = Wf32 + k0*D_ + n;
        bf16x8 bfr;
        #pragma unroll
        for (int j = 0; j < 8; j++) bfr[j] = (short)tobf_(src[j*D_]);
        acc[nt] = __builtin_amdgcn_mfma_f32_16x16x32_bf16(a, bfr, acc[nt], 0, 0, 0);
      }
    }
    const float* bias = (mat == 0) ? bup1 : bup2;
    #pragma unroll
    for (int nt = 0; nt < 4; nt++){
      #pragma unroll
      for (int r = 0; r < 4; r++){
        int m = lq*4 + r;
        int row = rt*16 + m;
        int e = w*64 + nt*16 + lm;
        float vv = acc[nt][r] + bias[e];
        if (mat == 1){
          trig[row*D_ + e] = silu_(vv);
        } else {
          xs[m][e] = vv;       // xinb written vectorized after sync
        }
      }
    }
    if (mat == 0){
      __syncthreads();
      // vectorized conv + xinb epilogue: thread -> (row m, 8-d octet), 2 passes
      int m = tid & 15;
      int oct2 = tid >> 4;               // 0..15
      int rowg = rt*16 + m;
      #pragma unroll
      for (int pass = 0; pass < 2; pass++){
        int d0 = (oct2 + pass*16) << 3;  // 0..248 step 8
        float xv[11];
        #pragma unroll
        for (int i = 0; i < 11; i++){
          int d = d0 - 1 + i;
          xv[i] = (d >= 0 && d <= 255) ? xs[m][d] : 0.f;
        }
        int fa = afrag_(rowg, d0);       // d0%8==0 -> 8 consecutive frag elems
        bf16x8 xo;
        #pragma unroll
        for (int j = 0; j < 8; j++) xo[j] = (short)tobf_(xv[j+1]);
        *(bf16x8*)(xinb + fa) = xo;
        #pragma unroll
        for (int h = 0; h < NH_; h++){
          float c0 = ck[0*NH_+h], c1 = ck[1*NH_+h], c2 = ck[2*NH_+h], c3 = ck[3*NH_+h];
          float cbh = cb[h];
          bf16x8 qv;
          #pragma unroll
          for (int j = 0; j < 8; j++){
            float a2 = cbh;
            a2 = fmaf(xv[j],   c0, a2);
            a2 = fmaf(xv[j+1], c1, a2);
            a2 = fmaf(xv[j+2], c2, a2);
            a2 = fmaf(xv[j+3], c3, a2);
            qv[j] = (short)tobf_(silu_(a2));
          }
          *(bf16x8*)(qkb + h*(TB_*D_) + fa) = qv;
        }
      }
      int dot = tid >> 2, l4 = tid & 3;
      int h = dot >> 4, mm = dot & 15;
      float ai = 0.f, af = 0.f;
      const float* wi = Wi + h*D_;
      const float* wf = Wf + h*D_;
      #pragma unroll 8
      for (int jj = 0; jj < 64; jj++){
        int k = l4*64 + jj;
        float xval = xs[mm][k];
        ai = fmaf(xval, wi[k], ai);
        af = fmaf(xval, wf[k], af);
      }
      ai += __shfl_down(ai, 1); af += __shfl_down(af, 1);
      ai += __shfl_down(ai, 2); af += __shfl_down(af, 2);
      if (l4 == 0){
        int rowg2 = rt*16 + mm;
        int t = rowg2 >> 3, b = rowg2 & 7;
        itb[(h*B_ + b)*T_ + t] = ai + bi[h];
        ftb[(h*B_ + b)*T_ + t] = af + bfv[h];
      }
    }
  } else if (bid < 704){
    // ---- big5 weight conversion (LDS-transpose tiles) ----
    int u = bid - 64;
    int sub = u & 31;
    int h   = (u >> 5) & 3;
    int mat = u >> 7;
    const float* Win; unsigned short* Wout;
    switch (mat){
      case 0: Win = Wq; Wout = Wqt; break;
      case 1: Win = Wk; Wout = Wkt; break;
      case 2: Win = Ws; Wout = Wst; break;
      case 3: Win = Wv; Wout = Wvt; break;
      default: Win = Wo; Wout = Wot; break;
    }
    conv_tile_(Win + h*(D_*D_), Wout + h*(D_*D_), D_, 8, sub & 15, sub >> 4, tl, tid);
  } else if (bid < 832){
    // ---- Wpoll [1024 x 256] -> B-frag K=1024 ----
    int u = bid - 704;                   // 0..127: tk = u&63, tn = u>>6
    conv_tile_(Wp, Wpt, D_, 32, u & 63, u >> 6, tl, tid);
  } else {
    // ---- Wdown [256 x 128] -> B-frag K=256 ----
    int u = bid - 832;                   // 0..15: tk = u, tn = 0
    conv_tile_(Wd, Wdt, H_, 8, u, 0, tl, tid);
  }
}

// ---------------- K2: per-head 5-matmul MFMA GEMM (verified) ----------------
__global__ __launch_bounds__(256) void k_gemm5(
    const unsigned short* __restrict__ qkb, const unsigned short* __restrict__ xinb,
    const unsigned short* __restrict__ Wqt, const unsigned short* __restrict__ Wkt,
    const unsigned short* __restrict__ Wst, const unsigned short* __restrict__ Wvt,
    const unsigned short* __restrict__ Wot,
    const float* __restrict__ bq, const float* __restrict__ bk, const float* __restrict__ bsk,
    const float* __restrict__ bv, const float* __restrict__ bo,
    unsigned short* __restrict__ qob, unsigned short* __restrict__ kob,
    unsigned short* __restrict__ vot,
    float* __restrict__ hb, float* __restrict__ og){
  int bid = blockIdx.x;
  int rt  = bid & 15;
  int h   = (bid >> 4) & 3;
  int mat = bid >> 6;                    // 0=q 1=k 2=skip 3=v 4=og
  int tid = threadIdx.x;
  int w = tid >> 6, l = tid & 63;
  int lm = l & 15, lq = l >> 4;
  int r0 = rt * 32;
  const unsigned short* A = (mat < 3) ? (qkb + h*(TB_*D_)) : xinb;
  const unsigned short* Bt;
  const float* bias;
  switch (mat){
    case 0: Bt = Wqt; bias = bq;  break;
    case 1: Bt = Wkt; bias = bk;  break;
    case 2: Bt = Wst; bias = bsk; break;
    case 3: Bt = Wvt; bias = bv;  break;
    default: Bt = Wot; bias = bo; break;
  }
  Bt += h*(D_*D_);
  f32x4 acc[2][4];
  #pragma unroll
  for (int mt = 0; mt < 2; mt++)
    #pragma unroll
    for (int nt = 0; nt < 4; nt++) acc[mt][nt] = (f32x4){0.f,0.f,0.f,0.f};
  const unsigned short* Ap = A + l*8;
  const unsigned short* Bp = Bt + l*8;
  #pragma unroll
  for (int kc = 0; kc < 8; kc++){
    bf16x8 a0 = *(const bf16x8*)(Ap + ((rt*16      + kc) << 9));
    bf16x8 a1 = *(const bf16x8*)(Ap + ((rt*16 + 8  + kc) << 9));
    bf16x8 b0 = *(const bf16x8*)(Bp + (((w*4+0)*8 + kc) << 9));
    bf16x8 b1 = *(const bf16x8*)(Bp + (((w*4+1)*8 + kc) << 9));
    bf16x8 b2 = *(const bf16x8*)(Bp + (((w*4+2)*8 + kc) << 9));
    bf16x8 b3 = *(const bf16x8*)(Bp + (((w*4+3)*8 + kc) << 9));
    acc[0][0] = __builtin_amdgcn_mfma_f32_16x16x32_bf16(a0, b0, acc[0][0], 0, 0, 0);
    acc[0][1] = __builtin_amdgcn_mfma_f32_16x16x32_bf16(a0, b1, acc[0][1], 0, 0, 0);
    acc[0][2] = __builtin_amdgcn_mfma_f32_16x16x32_bf16(a0, b2, acc[0][2], 0, 0, 0);
    acc[0][3] = __builtin_amdgcn_mfma_f32_16x16x32_bf16(a0, b3, acc[0][3], 0, 0, 0);
    acc[1][0] = __builtin_amdgcn_mfma_f32_16x16x32_bf16(a1, b0, acc[1][0], 0, 0, 0);
    acc[1][1] = __builtin_amdgcn_mfma_f32_16x16x32_bf16(a1, b1, acc[1][1], 0, 0, 0);
    acc[1][2] = __builtin_amdgcn_mfma_f32_16x16x32_bf16(a1, b2, acc[1][2], 0, 0, 0);
    acc[1][3] = __builtin_amdgcn_mfma_f32_16x16x32_bf16(a1, b3, acc[1][3], 0, 0, 0);
  }
  float bval[4];
  #pragma unroll
  for (int nt = 0; nt < 4; nt++) bval[nt] = bias[h*D_ + w*64 + nt*16 + lm];
  #pragma unroll
  for (int mt = 0; mt < 2; mt++){
    #pragma unroll
    for (int r = 0; r < 4; r++){
      int row = r0 + mt*16 + lq*4 + r;
      int t = row >> 3, b = row & 7;
      #pragma unroll
      for (int nt = 0; nt < 4; nt++){
        int e = w*64 + nt*16 + lm;
        float vv = acc[mt][nt][r] + bval[nt];
        if (mat <= 1){
          if (mat == 1) vv *= 0.0625f;
          unsigned short* ob = (mat == 0) ? qob : kob;
          int mt2 = t >> 4, kb2 = e >> 5;
          int lane2 = ((e >> 3)&3)*16 + (t & 15);
          ob[(h*B_ + b)*16384 + ((mt2*8 + kb2)*64 + lane2)*8 + (e & 7)] = tobf_(vv);
        } else if (mat == 3){
          int nt3 = e >> 4, kb3 = t >> 5;
          int lane3 = ((t >> 3)&3)*16 + lm;
          vot[(h*B_ + b)*16384 + ((nt3*2 + kb3)*64 + lane3)*8 + (t & 7)] = tobf_(vv);
        } else {
          int obase = (((t*NH_ + h)*B_ + b) << 8) + e;
          if (mat == 4) og[obase] = sigm_(vv);
          else          hb[obase] = vv;        // skip term
        }
      }
    }
  }
}

// ---------------- K3: MFMA attention with fused gate scan (verified) ----------------
__global__ __launch_bounds__(256) void k_attn2(
    const unsigned short* __restrict__ qob, const unsigned short* __restrict__ kob,
    const unsigned short* __restrict__ vot, const float* __restrict__ og,
    const float* __restrict__ itb, const float* __restrict__ ftb,
    float* __restrict__ hb){
  __shared__ unsigned short Pf[1024];
  __shared__ float partial[4][16];
  __shared__ float scal[16];
  int bid = blockIdx.x;
  int hbx = bid >> 2, tq = bid & 3;
  int h = hbx >> 3, b = hbx & 7;
  int tid = threadIdx.x;
  int w = tid >> 6, l = tid & 63, lm = l & 15, lq = l >> 4;
  float F  = ftb[hbx*T_ + l];
  float it = itb[hbx*T_ + l];
  #pragma unroll
  for (int off = 1; off < 64; off <<= 1){
    float v2 = __shfl_up(F, off);
    if (l >= off) F += v2;
  }
  float ct = it - F;
  float G = ct;
  #pragma unroll
  for (int off = 1; off < 64; off <<= 1){
    float v2 = __shfl_up(G, off);
    if (l >= off) G = fmaxf(G, v2);
  }
  float rb = -fmaxf(0.f, G);
  const unsigned short* Aq = qob + hbx*16384 + l*8;
  const unsigned short* Bk = kob + hbx*16384 + l*8;
  f32x4 accs = (f32x4){0.f,0.f,0.f,0.f};
  #pragma unroll
  for (int kc = 0; kc < 8; kc++){
    bf16x8 a  = *(const bf16x8*)(Aq + ((tq*8 + kc) << 9));
    bf16x8 bb = *(const bf16x8*)(Bk + ((w*8  + kc) << 9));
    accs = __builtin_amdgcn_mfma_f32_16x16x32_bf16(a, bb, accs, 0, 0, 0);
  }
  int s = w*16 + lm;
  float ct_s = __shfl(ct, s);
  float p[4], ps[4];
  #pragma unroll
  for (int r = 0; r < 4; r++){
    int t = tq*16 + lq*4 + r;
    float rb_t = __shfl(rb, t);
    float pv = (s <= t) ? __expf(ct_s + rb_t) * accs[r] : 0.f;
    p[r] = pv; ps[r] = pv;
  }
  #pragma unroll
  for (int off = 1; off < 16; off <<= 1){
    #pragma unroll
    for (int r = 0; r < 4; r++) ps[r] += __shfl_xor(ps[r], off);
  }
  if (lm == 0){
    #pragma unroll
    for (int r = 0; r < 4; r++) partial[w][lq*4 + r] = ps[r];
  }
  {
    int kbP = w >> 1;
    int laneP = ((w*2 + (lm >> 3)) & 3)*16;
    int jP = lm & 7;
    #pragma unroll
    for (int r = 0; r < 4; r++){
      int m = lq*4 + r;
      Pf[(kbP*64 + laneP + m)*8 + jP] = tobf_(p[r]);
    }
  }
  __syncthreads();
  if (tid < 16){
    float sum = partial[0][tid] + partial[1][tid] + partial[2][tid] + partial[3][tid];
    scal[tid] = 1.0f / fmaxf(fabsf(sum), 1.0f);
  }
  bf16x8 pa0 = *(const bf16x8*)(Pf + l*8);
  bf16x8 pa1 = *(const bf16x8*)(Pf + 512 + l*8);
  const unsigned short* Bv = vot + hbx*16384 + l*8;
  f32x4 acco[4];
  #pragma unroll
  for (int nt = 0; nt < 4; nt++) acco[nt] = (f32x4){0.f,0.f,0.f,0.f};
  #pragma unroll
  for (int nt = 0; nt < 4; nt++){
    int nt3 = w*4 + nt;
    bf16x8 b0 = *(const bf16x8*)(Bv + (((nt3*2 + 0)) << 9));
    bf16x8 b1 = *(const bf16x8*)(Bv + (((nt3*2 + 1)) << 9));
    acco[nt] = __builtin_amdgcn_mfma_f32_16x16x32_bf16(pa0, b0, acco[nt], 0, 0, 0);
    acco[nt] = __builtin_amdgcn_mfma_f32_16x16x32_bf16(pa1, b1, acco[nt], 0, 0, 0);
  }
  __syncthreads();
  #pragma unroll
  for (int nt = 0; nt < 4; nt++){
    #pragma unroll
    for (int r = 0; r < 4; r++){
      int tl = lq*4 + r;
      int t = tq*16 + tl;
      int e = (w*4 + nt)*16 + lm;
      int idx = (((t*NH_ + h)*B_ + b) << 8) + e;
      hb[idx] += og[idx] * acco[nt][r] * scal[tl];
    }
  }
}

// ---------------- K4: fused bn2 + poll(*trig) + down(+x)  (verified) ----------------
// grid 32 (one unit = 16 rows = 2 t's), 256 threads
__global__ __launch_bounds__(256) void k_tail3(
    const float* __restrict__ hbuf, const float* __restrict__ bn2s, const float* __restrict__ bn2b,
    const unsigned short* __restrict__ Wpt, const float* __restrict__ bp,
    const float* __restrict__ trig, const unsigned short* __restrict__ Wdt,
    const float* __restrict__ bd, const float* __restrict__ x, float* __restrict__ y){
  __shared__ unsigned short hfr[16384];   // A-frag M=16, K=1024 (32 KB)
  __shared__ unsigned short zf[4096];     // z frag M=16, K=256 (8 KB)
  int u = blockIdx.x;
  int tid = threadIdx.x;
  int w = tid >> 6, l = tid & 63, lm = l & 15, lq = l >> 4;
  #pragma unroll
  for (int s = 0; s < 2; s++){
    int pair = tid + (s << 8);     // 0..511
    int tt = pair >> 8;            // 0..1
    int d  = pair & 255;
    int t  = u*2 + tt;
    const float* hp = hbuf + (t*NH_*B_)*D_ + d;
    float v[32]; float mu = 0.f;
    #pragma unroll
    for (int i = 0; i < 32; i++){ v[i] = hp[i*D_]; mu += v[i]; }
    mu *= (1.0f/32.0f);
    float var = 0.f;
    #pragma unroll
    for (int i = 0; i < 32; i++){ float dd = v[i]-mu; var += dd*dd; }
    var *= (1.0f/32.0f);
    float sc = (1.0f/sqrtf(var + EPS_)) * bn2s[d];
    float bs = bn2b[d];
    #pragma unroll
    for (int i = 0; i < 32; i++){          // i = h*8 + b
      int hh = i >> 3, b = i & 7;
      int m = tt*8 + b;
      int k = hh*D_ + d;
      hfr[afrag1024_(m, k)] = tobf_((v[i]-mu)*sc + bs);
    }
  }
  __syncthreads();
  f32x4 acc[4];
  #pragma unroll
  for (int nt = 0; nt < 4; nt++) acc[nt] = (f32x4){0.f,0.f,0.f,0.f};
  const unsigned short* Apl = hfr + l*8;
  const unsigned short* Bp  = Wpt + l*8;
  #pragma unroll 4
  for (int kc = 0; kc < 32; kc++){
    bf16x8 a = *(const bf16x8*)(Apl + (kc << 9));
    #pragma unroll
    for (int nt = 0; nt < 4; nt++){
      bf16x8 bfr = *(const bf16x8*)(Bp + ((((w*4+nt)*32) + kc) << 9));
      acc[nt] = __builtin_amdgcn_mfma_f32_16x16x32_bf16(a, bfr, acc[nt], 0, 0, 0);
    }
  }
  #pragma unroll
  for (int nt = 0; nt < 4; nt++){
    int e = w*64 + nt*16 + lm;
    float bpe = bp[e];
    #pragma unroll
    for (int r = 0; r < 4; r++){
      int ml = lq*4 + r;
      int row = u*16 + ml;
      float z = (acc[nt][r] + bpe) * trig[row*D_ + e];
      zf[afrag_(ml, e)] = tobf_(z);
    }
  }
  __syncthreads();
  f32x4 acc2[2];
  acc2[0] = (f32x4){0.f,0.f,0.f,0.f};
  acc2[1] = (f32x4){0.f,0.f,0.f,0.f};
  const unsigned short* Bdp = Wdt + l*8;
  #pragma unroll
  for (int kc = 0; kc < 8; kc++){
    bf16x8 a = *(const bf16x8*)(zf + (kc << 9) + l*8);
    #pragma unroll
    for (int q = 0; q < 2; q++){
      bf16x8 bb = *(const bf16x8*)(Bdp + (((w*2+q)*8 + kc) << 9));
      acc2[q] = __builtin_amdgcn_mfma_f32_16x16x32_bf16(a, bb, acc2[q], 0, 0, 0);
    }
  }
  #pragma unroll
  for (int q = 0; q < 2; q++){
    int hh = (w*2+q)*16 + lm;
    float bde = bd[hh];
    #pragma unroll
    for (int r = 0; r < 4; r++){
      int row = u*16 + lq*4 + r;
      y[row*H_ + hh] = acc2[q][r] + bde + x[row*H_ + hh];
    }
  }
}

extern "C" void kernel_launch(void* const* d_in, const int* in_sizes, int n_in,
                              void* d_out, int out_size, void* d_ws, size_t ws_size,
                              hipStream_t stream){
  const float* x     = (const float*)d_in[0];
  const float* Wq    = (const float*)d_in[1];
  const float* bq    = (const float*)d_in[2];
  const float* Wk    = (const float*)d_in[3];
  const float* bk    = (const float*)d_in[4];
  const float* Wv    = (const float*)d_in[5];
  const float* bv    = (const float*)d_in[6];
  const float* ck    = (const float*)d_in[7];
  const float* cb    = (const float*)d_in[8];
  const float* Wi    = (const float*)d_in[9];
  const float* bi    = (const float*)d_in[10];
  const float* Wf    = (const float*)d_in[11];
  const float* bf    = (const float*)d_in[12];
  const float* Wo    = (const float*)d_in[13];
  const float* bo    = (const float*)d_in[14];
  const float* Wsk   = (const float*)d_in[15];
  const float* bsk   = (const float*)d_in[16];
  const float* bn1s  = (const float*)d_in[17];
  const float* bn1b  = (const float*)d_in[18];
  const float* bn2s  = (const float*)d_in[19];
  const float* bn2b  = (const float*)d_in[20];
  const float* Wup1  = (const float*)d_in[21];
  const float* bup1  = (const float*)d_in[22];
  const float* Wup2  = (const float*)d_in[23];
  const float* bup2  = (const float*)d_in[24];
  const float* Wp    = (const float*)d_in[25];
  const float* bp    = (const float*)d_in[26];
  const float* Wd    = (const float*)d_in[27];
  const float* bd    = (const float*)d_in[28];
  float* y = (float*)d_out;

  float* w = (float*)d_ws;
  float* trig = w;  w += T_*B_*D_;
  float* hbuf = w;  w += T_*NH_*B_*D_;
  float* og   = w;  w += T_*NH_*B_*D_;
  float* itb  = w;  w += NH_*B_*T_;
  float* ftb  = w;  w += NH_*B_*T_;
  unsigned short* xinb = (unsigned short*)w;  w += (T_*B_*D_)/2;
  unsigned short* qkb  = (unsigned short*)w;  w += (NH_*TB_*D_)/2;
  unsigned short* Wqt  = (unsigned short*)w;  w += (NH_*D_*D_)/2;
  unsigned short* Wkt  = (unsigned short*)w;  w += (NH_*D_*D_)/2;
  unsigned short* Wst  = (unsigned short*)w;  w += (NH_*D_*D_)/2;
  unsigned short* Wvt  = (unsigned short*)w;  w += (NH_*D_*D_)/2;
  unsigned short* Wot  = (unsigned short*)w;  w += (NH_*D_*D_)/2;
  unsigned short* qob  = (unsigned short*)w;  w += (NH_*B_*T_*D_)/2;
  unsigned short* kob  = (unsigned short*)w;  w += (NH_*B_*T_*D_)/2;
  unsigned short* vot  = (unsigned short*)w;  w += (NH_*B_*T_*D_)/2;
  unsigned short* Wpt  = (unsigned short*)w;  w += (NH_*D_*D_)/2;
  unsigned short* Wdt  = (unsigned short*)w;  w += (D_*H_)/2;

  k_prepup<<<848, 256, 0, stream>>>(Wq, Wk, Wsk, Wv, Wo, Wup1, Wup2, Wp, Wd,
                                    x, bn1s, bn1b, bup1, bup2, ck, cb, Wi, bi, Wf, bf,
                                    Wqt, Wkt, Wst, Wvt, Wot, Wpt, Wdt,
                                    xinb, qkb, trig, itb, ftb);
  k_gemm5<<<320, 256, 0, stream>>>(qkb, xinb, Wqt, Wkt, Wst, Wvt, Wot,
                                   bq, bk, bsk, bv, bo, qob, kob, vot, hbuf, og);
  k_attn2<<<NH_*B_*4, 256, 0, stream>>>(qob, kob, vot, og, itb, ftb, hbuf);
  k_tail3<<<32, 256, 0, stream>>>(hbuf, bn2s, bn2b, Wpt, bp, trig, Wdt, bd, x, y);
}